// Round 14
// baseline (130.963 us; speedup 1.0000x reference)
//
#include <hip/hip_runtime.h>
#include <hip/hip_bf16.h>

// Flash attention fwd, causal + key-padding, B=4 S=4096 D=64, fp32 in/out.
// Round 14: round-13 fused-merge design with the counter race FIXED:
// round 13's "(old+1) % nvalid == 0" trigger fires on the
// ((nvalid - v0 mod nvalid))-th arrival — NOT the last — when the poisoned
// counter v0 % nvalid != 0, so the merge read stale slots (absmax 2.83).
// Fix: hipMemsetAsync(cnt, 0) each launch (graph-capturable memset node)
// and trigger strictly on the last arrival (v == nvalid-1). Everything
// else byte-identical to round 13 (round-12 green inner loop).

#define S_LEN 4096
#define D_DIM 64
#define NBATCH 4
#define QBLK 128
#define KVBLK 64
#define NQB (S_LEN / QBLK)          // 32 q-blocks per batch
#define SLOT_B 17408                // 16K bf16 O + 1K fp32 m/l

typedef __attribute__((ext_vector_type(16))) float f32x16;
typedef __attribute__((ext_vector_type(4))) float f32x4;
typedef __attribute__((ext_vector_type(8))) short s16x8;
typedef __attribute__((ext_vector_type(4))) short s16x4;
typedef __attribute__((ext_vector_type(2))) unsigned int u32x2;

#define FK(n) ((((n) ^ ((n) >> 3)) & 7) << 4)                    // K swizzle
#define FV(d) (((((d) & 7) << 4)) ^ ((((d) >> 3) & 1) << 3))     // V^T swizzle

__device__ __forceinline__ unsigned short f2bfu(float f) {
  return __builtin_bit_cast(unsigned short, __float2bfloat16(f));
}
__device__ __forceinline__ unsigned pk2(float a, float b) {
  return (unsigned)f2bfu(a) | ((unsigned)f2bfu(b) << 16);
}
__device__ __forceinline__ float bf2f(short s) {
  return __builtin_bit_cast(float, ((unsigned)(unsigned short)s) << 16);
}

__global__ __launch_bounds__(256, 3) void fattn_partial(
    const float* __restrict__ Qg, const float* __restrict__ Kg,
    const float* __restrict__ Vg, const unsigned char* __restrict__ Pad,
    float* __restrict__ Og, char* __restrict__ Ws,
    unsigned* __restrict__ cnt, int CL, int TOTC)
{
  // Uniform partition: enumeration index u -> (Qb, ci); heavy-first.
  const int wid = blockIdx.x;
  const int b   = wid & 3;
  const int u   = TOTC - 1 - (wid >> 2);
  int Qb = 0, ci = 0, pre = 0;
  {
    int uu = u, q = 0;
    while (true) {
      const int nch = (2 * q + 2 + CL - 1) / CL;
      if (uu < nch) { ci = uu; break; }
      uu -= nch; ++q;
    }
    Qb  = q;
    pre = u - ci;                    // first chunk index of this q-block
  }
  const int q0     = Qb * QBLK;
  const int ntt    = 2 * Qb + 2;
  const int nvalid = (ntt + CL - 1) / CL;
  const int t0     = ci * CL;
  const int t1     = (t0 + CL < ntt) ? (t0 + CL) : ntt;

  const int tid = threadIdx.x;
  const int w   = tid >> 6;          // wave 0..3 -> q rows [q0+32w, q0+32w+32)
  const int l   = tid & 63;
  const int ql  = l & 31;
  const int hi  = l >> 5;
  const int qw0 = q0 + 32 * w;
  const int qa  = qw0 + ql;

  // staging roles (cover 64 rows x 16 float4 with 256 threads)
  const int sq  = l & 3;
  const int sm  = (l >> 2) & 3;
  const int sc2 = l >> 4;
  const int snb = 4 * w + 16 * sc2;  // n-chunk base (multiple of 4)

  __shared__ short Ksh[2][KVBLK * D_DIM];   // [n][d] bf16, FK-swizzled
  __shared__ short Vtsh[2][D_DIM * KVBLK];  // [d][n] bf16 (V^T), FV-swizzled
  __shared__ int flagSh;

  const unsigned char* PadB = Pad + (size_t)b * S_LEN;

  // ---- prologue: block-wide padding flag for this chunk's key range ----
  if (tid == 0) flagSh = 0;
  __syncthreads();
  {
    const int nk  = (t1 - t0) * KVBLK;      // <= 512
    const int idx = 2 * tid;
    if (idx < nk) {
      const unsigned char* pp = PadB + t0 * KVBLK + idx;
      const bool nz = pp[0] || ((idx + 1 < nk) ? pp[1] : (unsigned char)0);
      if (nz) flagSh = 1;                   // benign same-value race
    }
  }

  // ---- Q fragments (B-operand), pre-scaled by 1/8 ----
  s16x8 qf[4];
  {
    const float* qp = Qg + ((size_t)(b * S_LEN + qa)) * D_DIM + 8 * hi;
    #pragma unroll
    for (int dc = 0; dc < 4; ++dc)
      #pragma unroll
      for (int j = 0; j < 8; ++j)
        qf[dc][j] = (short)f2bfu(qp[16 * dc + j] * 0.125f);
  }

  f32x16 acc[2];
  #pragma unroll
  for (int dt = 0; dt < 2; ++dt)
    #pragma unroll
    for (int i = 0; i < 16; ++i) acc[dt][i] = 0.f;
  float mrow = -INFINITY;
  float lrow = 0.f;

  u32x2 kpb[4], vpb[4];   // bf16-packed prefetch (converted at load)

#define LOAD_K(T) do {                                                       \
    const int kv0_ = (T) * KVBLK;                                            \
    _Pragma("unroll")                                                        \
    for (int s_ = 0; s_ < 4; ++s_) {                                         \
      const size_t go_ =                                                     \
          ((size_t)(b * S_LEN + kv0_ + snb + sq)) * D_DIM + 16 * s_ + 4 * sm;\
      const float4 kx = *(const float4*)(Kg + go_);                          \
      kpb[s_][0] = pk2(kx.x, kx.y); kpb[s_][1] = pk2(kx.z, kx.w);            \
    }                                                                        \
  } while (0)

#define LOAD_V(T) do {                                                       \
    const int kv0_ = (T) * KVBLK;                                            \
    _Pragma("unroll")                                                        \
    for (int s_ = 0; s_ < 4; ++s_) {                                         \
      const size_t go_ =                                                     \
          ((size_t)(b * S_LEN + kv0_ + snb + sq)) * D_DIM + 16 * s_ + 4 * sm;\
      const float4 vx = *(const float4*)(Vg + go_);                          \
      vpb[s_][0] = pk2(vx.x, vx.y); vpb[s_][1] = pk2(vx.z, vx.w);            \
    }                                                                        \
  } while (0)

#define STAGE(BUF) do {                                                      \
    _Pragma("unroll")                                                        \
    for (int s_ = 0; s_ < 4; ++s_) {                                         \
      const int d0_ = 16 * s_ + 4 * sm; const int nk_ = snb + sq;            \
      *(u32x2*)((char*)&Ksh[BUF][0] + nk_ * 128 + ((2 * d0_) ^ FK(nk_))) =   \
          kpb[s_];                                                           \
      unsigned u0 = vpb[s_][0], u1 = vpb[s_][1];                             \
      unsigned x_ = (sq & 2) ? u0 : u1;                                      \
      unsigned y_ = __shfl_xor(x_, 2);                                       \
      unsigned A0 = (sq & 2) ? y_ : u0;                                      \
      unsigned A1 = (sq & 2) ? u1 : y_;                                      \
      unsigned z0 = __shfl_xor(A0, 1);                                       \
      unsigned z1 = __shfl_xor(A1, 1);                                       \
      unsigned o0, o1;                                                       \
      if (sq & 1) { o0 = (z0 >> 16) | (A0 & 0xFFFF0000u);                    \
                    o1 = (z1 >> 16) | (A1 & 0xFFFF0000u); }                  \
      else        { o0 = (A0 & 0xFFFFu) | (z0 << 16);                        \
                    o1 = (A1 & 0xFFFFu) | (z1 << 16); }                      \
      const int dv_ = d0_ + sq;                                              \
      u32x2 vv2; vv2[0] = o0; vv2[1] = o1;                                   \
      *(u32x2*)((char*)&Vtsh[BUF][0] + dv_ * 128 + ((2 * snb) ^ FV(dv_))) = vv2;\
    }                                                                        \
  } while (0)

  LOAD_K(t0);
  LOAD_V(t0);
  STAGE(0);
  __syncthreads();
  const bool hasPad = (flagSh != 0);
  int cb = 0;

  for (int t = t0; t < t1; ++t) {
    const int kv0 = t * KVBLK;
    const bool more = (t + 1 < t1);
    if (more) LOAD_K(t + 1);

    // ---- S^T = mfma(A=K, B=Q): col=lane&31=q, row=k ----
    f32x16 sv[2];
    __builtin_amdgcn_s_setprio(1);
    #pragma unroll
    for (int kt = 0; kt < 2; ++kt) {
      f32x16 a;
      #pragma unroll
      for (int i = 0; i < 16; ++i) a[i] = 0.f;
      #pragma unroll
      for (int dc = 0; dc < 4; ++dc) {
        const int nr = 32 * kt + ql;
        const s16x8 kf = *(const s16x8*)((char*)&Ksh[cb][0] + nr * 128 +
                                         ((32 * dc + 16 * hi) ^ FK(nr)));
        a = __builtin_amdgcn_mfma_f32_32x32x16_bf16(kf, qf[dc], a, 0, 0, 0);
      }
      sv[kt] = a;
    }
    __builtin_amdgcn_s_setprio(0);

    if (more) LOAD_V(t + 1);

    // ---- padding (rare path) ----
    if (hasPad) {
      #pragma unroll
      for (int kt = 0; kt < 2; ++kt)
        #pragma unroll
        for (int r1 = 0; r1 < 4; ++r1) {
          const unsigned pd =
              *(const unsigned*)(PadB + kv0 + 32 * kt + 8 * r1 + 4 * hi);
          #pragma unroll
          for (int r0 = 0; r0 < 4; ++r0)
            if ((pd >> (8 * r0)) & 0xFFu) sv[kt][4 * r1 + r0] = -1e30f;
        }
    }
    // ---- causal mask (diagonal band only): k = kv0+32kt+8r1+4hi+r0 ----
    #pragma unroll
    for (int kt = 0; kt < 2; ++kt) {
      const int kvt = kv0 + 32 * kt;
      if (kvt + 31 > qw0) {
        #pragma unroll
        for (int r1 = 0; r1 < 4; ++r1)
          #pragma unroll
          for (int r0 = 0; r0 < 4; ++r0)
            if (kvt + 8 * r1 + 4 * hi + r0 > qa) sv[kt][4 * r1 + r0] = -1e30f;
      }
    }

    // ---- in-register online softmax: TREE max, 4-way sum ----
    f32x16 mx;
    #pragma unroll
    for (int i = 0; i < 16; ++i) mx[i] = fmaxf(sv[0][i], sv[1][i]);
    f32x4 m4;
    #pragma unroll
    for (int i = 0; i < 4; ++i)
      m4[i] = fmaxf(fmaxf(mx[i], mx[i + 4]), fmaxf(mx[i + 8], mx[i + 12]));
    float vm = fmaxf(fmaxf(m4[0], m4[1]), fmaxf(m4[2], m4[3]));
    vm = fmaxf(vm, __shfl_xor(vm, 32));           // merge across hi halves
    const float mn   = fmaxf(mrow, vm);
    const float corr = __expf(mrow - mn);
    mrow = mn;
    lrow *= corr;
    #pragma unroll
    for (int dt = 0; dt < 2; ++dt)
      #pragma unroll
      for (int i = 0; i < 16; ++i) acc[dt][i] *= corr;

    float rs0 = 0.f, rs1 = 0.f, rs2 = 0.f, rs3 = 0.f;
    #pragma unroll
    for (int kt = 0; kt < 2; ++kt)
      #pragma unroll
      for (int i4 = 0; i4 < 16; i4 += 4) {
        const float p0 = __expf(sv[kt][i4 + 0] - mn);
        const float p1 = __expf(sv[kt][i4 + 1] - mn);
        const float p2 = __expf(sv[kt][i4 + 2] - mn);
        const float p3 = __expf(sv[kt][i4 + 3] - mn);
        sv[kt][i4 + 0] = p0; sv[kt][i4 + 1] = p1;
        sv[kt][i4 + 2] = p2; sv[kt][i4 + 3] = p3;
        rs0 += p0; rs1 += p1; rs2 += p2; rs3 += p3;
      }
    lrow += (rs0 + rs1) + (rs2 + rs3);            // own half-sum only

    // ---- O^T += mfma(A=V^T, B=P) ----
    // P B-frag in C/D-native k-order: elem j <-> k = 4hi+(j&3)+8*(j>>2).
    // V^T A-frag reads the SAME element->k map (two 8B LDS reads).
    __builtin_amdgcn_s_setprio(1);
    #pragma unroll
    for (int sk = 0; sk < 4; ++sk) {
      const int kt = sk >> 1, rb = 8 * (sk & 1);
      union { unsigned u[4]; s16x8 v; } pb;
      pb.u[0] = pk2(sv[kt][rb + 0], sv[kt][rb + 1]);
      pb.u[1] = pk2(sv[kt][rb + 2], sv[kt][rb + 3]);
      pb.u[2] = pk2(sv[kt][rb + 4], sv[kt][rb + 5]);
      pb.u[3] = pk2(sv[kt][rb + 6], sv[kt][rb + 7]);
      #pragma unroll
      for (int dt = 0; dt < 2; ++dt) {
        const int dr = 32 * dt + ql;
        const char* vrow = (char*)&Vtsh[cb][0] + dr * 128;
        const s16x4 v0 = *(const s16x4*)(vrow + ((32 * sk + 8 * hi) ^ FV(dr)));
        const s16x4 v1 = *(const s16x4*)(vrow + ((32 * sk + 16 + 8 * hi) ^ FV(dr)));
        s16x8 vf;
        vf[0] = v0[0]; vf[1] = v0[1]; vf[2] = v0[2]; vf[3] = v0[3];
        vf[4] = v1[0]; vf[5] = v1[1]; vf[6] = v1[2]; vf[7] = v1[3];
        acc[dt] = __builtin_amdgcn_mfma_f32_32x32x16_bf16(vf, pb.v, acc[dt], 0, 0, 0);
      }
    }
    __builtin_amdgcn_s_setprio(0);

    if (more) STAGE(cb ^ 1);
    __syncthreads();
    cb ^= 1;
  }

  // ---- epilogue: merge l across hi halves ----
  const float lt = lrow + __shfl_xor(lrow, 32);

  if (nvalid == 1) {
    // single chunk: write O directly, skip slot + counter
    const float inv = 1.0f / lt;
    #pragma unroll
    for (int dt = 0; dt < 2; ++dt)
      #pragma unroll
      for (int r1 = 0; r1 < 4; ++r1) {
        f32x4 o;
        #pragma unroll
        for (int r0 = 0; r0 < 4; ++r0) o[r0] = acc[dt][4 * r1 + r0] * inv;
        *(f32x4*)(Og + ((size_t)(b * S_LEN + qa)) * D_DIM +
                  32 * dt + 8 * r1 + 4 * hi) = o;
      }
    return;
  }

  // ---- write bf16 partial slot ----
  char* slot = Ws + ((size_t)b * TOTC + u) * SLOT_B;
  const int row = 32 * w + ql;
  #pragma unroll
  for (int dt = 0; dt < 2; ++dt)
    #pragma unroll
    for (int r1 = 0; r1 < 4; ++r1) {
      u32x2 p;
      p[0] = pk2(acc[dt][4 * r1 + 0], acc[dt][4 * r1 + 1]);
      p[1] = pk2(acc[dt][4 * r1 + 2], acc[dt][4 * r1 + 3]);
      *(u32x2*)(slot + row * 128 + (32 * dt + 8 * r1 + 4 * hi) * 2) = p;
    }
  if (hi == 0) {
    ((float*)(slot + 16384))[row]       = mrow;
    ((float*)(slot + 16384 + 512))[row] = lt;
  }

  // ---- fused merge: LAST finisher of this q-block merges all chunks ----
  __syncthreads();
  if (tid == 0) {
    __threadfence();                              // release slot writes
    const unsigned v = atomicAdd(&cnt[b * NQB + Qb], 1u);
    flagSh = (v == (unsigned)(nvalid - 1)) ? 1 : 0;   // strictly last
  }
  __syncthreads();
  if (!flagSh) return;
  __threadfence();                                // acquire others' slots

  const int mr = tid >> 1;                        // q row 0..127
  const int md = (tid & 1) << 5;                  // 32 d-elems per thread
  const char* mbase = Ws + ((size_t)b * TOTC + pre) * SLOT_B;

  float mstar = -INFINITY;
  for (int c2 = 0; c2 < nvalid; ++c2)
    mstar = fmaxf(mstar,
                  ((const float*)(mbase + (size_t)c2 * SLOT_B + 16384))[mr]);

  float lsum = 0.f;
  float o[32];
  #pragma unroll
  for (int k = 0; k < 32; ++k) o[k] = 0.f;

  for (int c2 = 0; c2 < nvalid; ++c2) {
    const char* sl = mbase + (size_t)c2 * SLOT_B;
    const float wgt = __expf(((const float*)(sl + 16384))[mr] - mstar);
    lsum += wgt * ((const float*)(sl + 16384 + 512))[mr];
    #pragma unroll
    for (int g8 = 0; g8 < 4; ++g8) {
      const s16x8 ov = *(const s16x8*)(sl + mr * 128 + (md + 8 * g8) * 2);
      #pragma unroll
      for (int k = 0; k < 8; ++k) o[8 * g8 + k] += wgt * bf2f(ov[k]);
    }
  }

  const float inv = 1.0f / lsum;
  float* op = Og + ((size_t)(b * S_LEN + q0 + mr)) * D_DIM + md;
  #pragma unroll
  for (int g4 = 0; g4 < 8; ++g4) {
    f32x4 ov;
    #pragma unroll
    for (int k = 0; k < 4; ++k) ov[k] = o[4 * g4 + k] * inv;
    *(f32x4*)(op + 4 * g4) = ov;
  }
}

extern "C" void kernel_launch(void* const* d_in, const int* in_sizes, int n_in,
                              void* d_out, int out_size, void* d_ws, size_t ws_size,
                              hipStream_t stream) {
  const float* Q = (const float*)d_in[0];
  const float* K = (const float*)d_in[1];
  const float* V = (const float*)d_in[2];
  const unsigned char* P = (const unsigned char*)d_in[3];
  float* O  = (float*)d_out;
  char*  Ws = (char*)d_ws;

  // chunk length CL=4 if slot pool + counters fit, else 8
  int CL = 4;
  int TOTC = 0;
  for (int q = 0; q < NQB; ++q) TOTC += (2 * q + 2 + CL - 1) / CL;   // 272
  if (ws_size < (size_t)NBATCH * TOTC * SLOT_B + 512) {
    CL = 8;
    TOTC = 0;
    for (int q = 0; q < NQB; ++q) TOTC += (2 * q + 2 + CL - 1) / CL; // 144
  }
  unsigned* cnt = (unsigned*)(Ws + (size_t)NBATCH * TOTC * SLOT_B);

  // Deterministic counter init each launch (graph-capturable memset node).
  hipMemsetAsync(cnt, 0, NBATCH * NQB * sizeof(unsigned), stream);

  dim3 grid(NBATCH * TOTC);
  dim3 block(256);
  hipLaunchKernelGGL(fattn_partial, grid, block, 0, stream, Q, K, V, P, O, Ws,
                     cnt, CL, TOTC);
}

// Round 15
// 59.044 us; speedup vs baseline: 2.2181x; 2.2181x over previous
//
#include <hip/hip_runtime.h>
#include <hip/hip_bf16.h>

// Flash attention fwd, causal + key-padding, B=4 S=4096 D=64, fp32 in/out.
// Round 15: round-12 green base (two-kernel, uniform CL-tile partition,
// bf16-at-load staging, tree-max/4-way-sum softmax, bf16 partial slots)
// with SINGLE-BUFFER LDS staging (16.6KB vs 33.3KB dbuf): LDS cap rises
// 4 -> 6 blocks/CU (VGPR 84 = 6 waves/SIMD). Register prefetch already
// decouples global latency; cost is one extra barrier/iter (rounds-1-3
// pattern, green). Round 14's fused merge is abandoned: its per-block
// __threadfence L2-writeback thrashed caches (FETCH 13->24MB, 131us).

#define S_LEN 4096
#define D_DIM 64
#define NBATCH 4
#define QBLK 128
#define KVBLK 64
#define NQB (S_LEN / QBLK)          // 32 q-blocks per batch
#define SLOT_B 17408                // 16K bf16 O + 1K fp32 m/l

typedef __attribute__((ext_vector_type(16))) float f32x16;
typedef __attribute__((ext_vector_type(4))) float f32x4;
typedef __attribute__((ext_vector_type(8))) short s16x8;
typedef __attribute__((ext_vector_type(4))) short s16x4;
typedef __attribute__((ext_vector_type(2))) unsigned int u32x2;

#define FK(n) ((((n) ^ ((n) >> 3)) & 7) << 4)                    // K swizzle
#define FV(d) (((((d) & 7) << 4)) ^ ((((d) >> 3) & 1) << 3))     // V^T swizzle

__device__ __forceinline__ unsigned short f2bfu(float f) {
  return __builtin_bit_cast(unsigned short, __float2bfloat16(f));
}
__device__ __forceinline__ unsigned pk2(float a, float b) {
  return (unsigned)f2bfu(a) | ((unsigned)f2bfu(b) << 16);
}
__device__ __forceinline__ float bf2f(short s) {
  return __builtin_bit_cast(float, ((unsigned)(unsigned short)s) << 16);
}

__global__ __launch_bounds__(256, 3) void fattn_partial(
    const float* __restrict__ Qg, const float* __restrict__ Kg,
    const float* __restrict__ Vg, const unsigned char* __restrict__ Pad,
    char* __restrict__ Ws, int CL, int TOTC)
{
  // Uniform partition: enumeration index u -> (Qb, ci); heavy-first.
  const int wid = blockIdx.x;
  const int b   = wid & 3;
  const int u   = TOTC - 1 - (wid >> 2);
  int Qb = 0, ci = 0;
  {
    int uu = u, q = 0;
    while (true) {
      const int nch = (2 * q + 2 + CL - 1) / CL;
      if (uu < nch) { ci = uu; break; }
      uu -= nch; ++q;
    }
    Qb = q;
  }
  const int q0  = Qb * QBLK;
  const int ntt = 2 * Qb + 2;
  const int t0  = ci * CL;
  const int t1  = (t0 + CL < ntt) ? (t0 + CL) : ntt;

  const int tid = threadIdx.x;
  const int w   = tid >> 6;          // wave 0..3 -> q rows [q0+32w, q0+32w+32)
  const int l   = tid & 63;
  const int ql  = l & 31;
  const int hi  = l >> 5;
  const int qw0 = q0 + 32 * w;
  const int qa  = qw0 + ql;

  // staging roles (cover 64 rows x 16 float4 with 256 threads)
  const int sq  = l & 3;
  const int sm  = (l >> 2) & 3;
  const int sc2 = l >> 4;
  const int snb = 4 * w + 16 * sc2;  // n-chunk base (multiple of 4)

  __shared__ short Ksh[KVBLK * D_DIM];    // [n][d] bf16, FK-swizzled
  __shared__ short Vtsh[D_DIM * KVBLK];   // [d][n] bf16 (V^T), FV-swizzled
  __shared__ int anyPadSh;

  const unsigned char* PadB = Pad + (size_t)b * S_LEN;

  // ---- prologue: block-wide padding flag for this chunk's key range ----
  if (tid == 0) anyPadSh = 0;
  __syncthreads();
  {
    const int nk  = (t1 - t0) * KVBLK;      // <= 512
    const int idx = 2 * tid;
    if (idx < nk) {
      const unsigned char* pp = PadB + t0 * KVBLK + idx;
      const bool nz = pp[0] || ((idx + 1 < nk) ? pp[1] : (unsigned char)0);
      if (nz) anyPadSh = 1;                 // benign same-value race
    }
  }

  // ---- Q fragments (B-operand), pre-scaled by 1/8 ----
  s16x8 qf[4];
  {
    const float* qp = Qg + ((size_t)(b * S_LEN + qa)) * D_DIM + 8 * hi;
    #pragma unroll
    for (int dc = 0; dc < 4; ++dc)
      #pragma unroll
      for (int j = 0; j < 8; ++j)
        qf[dc][j] = (short)f2bfu(qp[16 * dc + j] * 0.125f);
  }

  f32x16 acc[2];
  #pragma unroll
  for (int dt = 0; dt < 2; ++dt)
    #pragma unroll
    for (int i = 0; i < 16; ++i) acc[dt][i] = 0.f;
  float mrow = -INFINITY;
  float lrow = 0.f;

  u32x2 kpb[4], vpb[4];   // bf16-packed prefetch (converted at load)

#define LOAD_KV(T) do {                                                      \
    const int kv0_ = (T) * KVBLK;                                            \
    _Pragma("unroll")                                                        \
    for (int s_ = 0; s_ < 4; ++s_) {                                         \
      const size_t go_ =                                                     \
          ((size_t)(b * S_LEN + kv0_ + snb + sq)) * D_DIM + 16 * s_ + 4 * sm;\
      const float4 kx = *(const float4*)(Kg + go_);                          \
      const float4 vx = *(const float4*)(Vg + go_);                          \
      kpb[s_][0] = pk2(kx.x, kx.y); kpb[s_][1] = pk2(kx.z, kx.w);            \
      vpb[s_][0] = pk2(vx.x, vx.y); vpb[s_][1] = pk2(vx.z, vx.w);            \
    }                                                                        \
  } while (0)

#define STAGE() do {                                                         \
    _Pragma("unroll")                                                        \
    for (int s_ = 0; s_ < 4; ++s_) {                                         \
      const int d0_ = 16 * s_ + 4 * sm; const int nk_ = snb + sq;            \
      *(u32x2*)((char*)&Ksh[0] + nk_ * 128 + ((2 * d0_) ^ FK(nk_))) =        \
          kpb[s_];                                                           \
      unsigned u0 = vpb[s_][0], u1 = vpb[s_][1];                             \
      unsigned x_ = (sq & 2) ? u0 : u1;                                      \
      unsigned y_ = __shfl_xor(x_, 2);                                       \
      unsigned A0 = (sq & 2) ? y_ : u0;                                      \
      unsigned A1 = (sq & 2) ? u1 : y_;                                      \
      unsigned z0 = __shfl_xor(A0, 1);                                       \
      unsigned z1 = __shfl_xor(A1, 1);                                       \
      unsigned o0, o1;                                                       \
      if (sq & 1) { o0 = (z0 >> 16) | (A0 & 0xFFFF0000u);                    \
                    o1 = (z1 >> 16) | (A1 & 0xFFFF0000u); }                  \
      else        { o0 = (A0 & 0xFFFFu) | (z0 << 16);                        \
                    o1 = (A1 & 0xFFFFu) | (z1 << 16); }                      \
      const int dv_ = d0_ + sq;                                              \
      u32x2 vv2; vv2[0] = o0; vv2[1] = o1;                                   \
      *(u32x2*)((char*)&Vtsh[0] + dv_ * 128 + ((2 * snb) ^ FV(dv_))) = vv2;  \
    }                                                                        \
  } while (0)

  LOAD_KV(t0);

  for (int t = t0; t < t1; ++t) {
    STAGE();                          // write prefetched tile to LDS
    __syncthreads();                  // staging visible to all waves
    const bool more = (t + 1 < t1);
    if (more) LOAD_KV(t + 1);         // prefetch next tile into regs

    const int kv0 = t * KVBLK;

    // ---- S^T = mfma(A=K, B=Q): col=lane&31=q, row=k ----
    f32x16 sv[2];
    __builtin_amdgcn_s_setprio(1);
    #pragma unroll
    for (int kt = 0; kt < 2; ++kt) {
      f32x16 a;
      #pragma unroll
      for (int i = 0; i < 16; ++i) a[i] = 0.f;
      #pragma unroll
      for (int dc = 0; dc < 4; ++dc) {
        const int nr = 32 * kt + ql;
        const s16x8 kf = *(const s16x8*)((char*)&Ksh[0] + nr * 128 +
                                         ((32 * dc + 16 * hi) ^ FK(nr)));
        a = __builtin_amdgcn_mfma_f32_32x32x16_bf16(kf, qf[dc], a, 0, 0, 0);
      }
      sv[kt] = a;
    }
    __builtin_amdgcn_s_setprio(0);

    // ---- padding (rare path) ----
    if (anyPadSh) {
      #pragma unroll
      for (int kt = 0; kt < 2; ++kt)
        #pragma unroll
        for (int r1 = 0; r1 < 4; ++r1) {
          const unsigned pd =
              *(const unsigned*)(PadB + kv0 + 32 * kt + 8 * r1 + 4 * hi);
          #pragma unroll
          for (int r0 = 0; r0 < 4; ++r0)
            if ((pd >> (8 * r0)) & 0xFFu) sv[kt][4 * r1 + r0] = -1e30f;
        }
    }
    // ---- causal mask (diagonal band only): k = kv0+32kt+8r1+4hi+r0 ----
    #pragma unroll
    for (int kt = 0; kt < 2; ++kt) {
      const int kvt = kv0 + 32 * kt;
      if (kvt + 31 > qw0) {
        #pragma unroll
        for (int r1 = 0; r1 < 4; ++r1)
          #pragma unroll
          for (int r0 = 0; r0 < 4; ++r0)
            if (kvt + 8 * r1 + 4 * hi + r0 > qa) sv[kt][4 * r1 + r0] = -1e30f;
      }
    }

    // ---- in-register online softmax: TREE max, 4-way sum ----
    f32x16 mx;
    #pragma unroll
    for (int i = 0; i < 16; ++i) mx[i] = fmaxf(sv[0][i], sv[1][i]);
    f32x4 m4;
    #pragma unroll
    for (int i = 0; i < 4; ++i)
      m4[i] = fmaxf(fmaxf(mx[i], mx[i + 4]), fmaxf(mx[i + 8], mx[i + 12]));
    float vm = fmaxf(fmaxf(m4[0], m4[1]), fmaxf(m4[2], m4[3]));
    vm = fmaxf(vm, __shfl_xor(vm, 32));           // merge across hi halves
    const float mn   = fmaxf(mrow, vm);
    const float corr = __expf(mrow - mn);
    mrow = mn;
    lrow *= corr;
    #pragma unroll
    for (int dt = 0; dt < 2; ++dt)
      #pragma unroll
      for (int i = 0; i < 16; ++i) acc[dt][i] *= corr;

    float rs0 = 0.f, rs1 = 0.f, rs2 = 0.f, rs3 = 0.f;
    #pragma unroll
    for (int kt = 0; kt < 2; ++kt)
      #pragma unroll
      for (int i4 = 0; i4 < 16; i4 += 4) {
        const float p0 = __expf(sv[kt][i4 + 0] - mn);
        const float p1 = __expf(sv[kt][i4 + 1] - mn);
        const float p2 = __expf(sv[kt][i4 + 2] - mn);
        const float p3 = __expf(sv[kt][i4 + 3] - mn);
        sv[kt][i4 + 0] = p0; sv[kt][i4 + 1] = p1;
        sv[kt][i4 + 2] = p2; sv[kt][i4 + 3] = p3;
        rs0 += p0; rs1 += p1; rs2 += p2; rs3 += p3;
      }
    lrow += (rs0 + rs1) + (rs2 + rs3);            // own half-sum only

    // ---- O^T += mfma(A=V^T, B=P) ----
    // P B-frag in C/D-native k-order: elem j <-> k = 4hi+(j&3)+8*(j>>2).
    // V^T A-frag reads the SAME element->k map (two 8B LDS reads).
    __builtin_amdgcn_s_setprio(1);
    #pragma unroll
    for (int sk = 0; sk < 4; ++sk) {
      const int kt = sk >> 1, rb = 8 * (sk & 1);
      union { unsigned u[4]; s16x8 v; } pb;
      pb.u[0] = pk2(sv[kt][rb + 0], sv[kt][rb + 1]);
      pb.u[1] = pk2(sv[kt][rb + 2], sv[kt][rb + 3]);
      pb.u[2] = pk2(sv[kt][rb + 4], sv[kt][rb + 5]);
      pb.u[3] = pk2(sv[kt][rb + 6], sv[kt][rb + 7]);
      #pragma unroll
      for (int dt = 0; dt < 2; ++dt) {
        const int dr = 32 * dt + ql;
        const char* vrow = (char*)&Vtsh[0] + dr * 128;
        const s16x4 v0 = *(const s16x4*)(vrow + ((32 * sk + 8 * hi) ^ FV(dr)));
        const s16x4 v1 = *(const s16x4*)(vrow + ((32 * sk + 16 + 8 * hi) ^ FV(dr)));
        s16x8 vf;
        vf[0] = v0[0]; vf[1] = v0[1]; vf[2] = v0[2]; vf[3] = v0[3];
        vf[4] = v1[0]; vf[5] = v1[1]; vf[6] = v1[2]; vf[7] = v1[3];
        acc[dt] = __builtin_amdgcn_mfma_f32_32x32x16_bf16(vf, pb.v, acc[dt], 0, 0, 0);
      }
    }
    __builtin_amdgcn_s_setprio(0);

    __syncthreads();                  // all waves done reading before restage
  }

  // ---- epilogue: merge l across hi halves; write bf16 partial slot ----
  const float lt = lrow + __shfl_xor(lrow, 32);

  char* slot = Ws + ((size_t)b * TOTC + u) * SLOT_B;
  const int row = 32 * w + ql;
  #pragma unroll
  for (int dt = 0; dt < 2; ++dt)
    #pragma unroll
    for (int r1 = 0; r1 < 4; ++r1) {
      u32x2 p;
      p[0] = pk2(acc[dt][4 * r1 + 0], acc[dt][4 * r1 + 1]);
      p[1] = pk2(acc[dt][4 * r1 + 2], acc[dt][4 * r1 + 3]);
      *(u32x2*)(slot + row * 128 + (32 * dt + 8 * r1 + 4 * hi) * 2) = p;
    }
  if (hi == 0) {
    ((float*)(slot + 16384))[row]       = mrow;
    ((float*)(slot + 16384 + 512))[row] = lt;
  }
}

__global__ __launch_bounds__(256, 8) void fattn_merge(
    const char* __restrict__ Ws, float* __restrict__ Og, int CL, int TOTC)
{
  const int blk = blockIdx.x;            // 512 = 128 qb * 4 quarters
  const int qbi = blk >> 2;
  const int qr  = blk & 3;
  const int Qb  = qbi & (NQB - 1);
  const int b   = qbi >> 5;
  const int tid = threadIdx.x;
  const int row = 32 * qr + (tid >> 3);  // q row within 128-block
  const int d0  = (tid & 7) * 8;         // 8 d-elems per thread

  const int ntt    = 2 * Qb + 2;
  const int nvalid = (ntt + CL - 1) / CL;
  int pre = 0;
  for (int q = 0; q < Qb; ++q) pre += (2 * q + 2 + CL - 1) / CL;

  const char* base = Ws + ((size_t)b * TOTC + pre) * SLOT_B;

  float mstar = -INFINITY;
  for (int ci = 0; ci < nvalid; ++ci)
    mstar = fmaxf(mstar, ((const float*)(base + (size_t)ci * SLOT_B + 16384))[row]);

  float lsum = 0.f;
  float o[8];
  #pragma unroll
  for (int k = 0; k < 8; ++k) o[k] = 0.f;

  for (int ci = 0; ci < nvalid; ++ci) {
    const char* slot = base + (size_t)ci * SLOT_B;
    const float wgt = __expf(((const float*)(slot + 16384))[row] - mstar);
    lsum += wgt * ((const float*)(slot + 16384 + 512))[row];
    const s16x8 ov = *(const s16x8*)(slot + row * 128 + d0 * 2);
    #pragma unroll
    for (int k = 0; k < 8; ++k) o[k] += wgt * bf2f(ov[k]);
  }

  const float inv = 1.0f / lsum;
  float* op = Og + ((size_t)(b * S_LEN + Qb * QBLK + row)) * D_DIM + d0;
  f32x4 o0, o1;
  #pragma unroll
  for (int k = 0; k < 4; ++k) { o0[k] = o[k] * inv; o1[k] = o[4 + k] * inv; }
  *(f32x4*)(op) = o0;
  *(f32x4*)(op + 4) = o1;
}

extern "C" void kernel_launch(void* const* d_in, const int* in_sizes, int n_in,
                              void* d_out, int out_size, void* d_ws, size_t ws_size,
                              hipStream_t stream) {
  const float* Q = (const float*)d_in[0];
  const float* K = (const float*)d_in[1];
  const float* V = (const float*)d_in[2];
  const unsigned char* P = (const unsigned char*)d_in[3];
  float* O  = (float*)d_out;
  char*  Ws = (char*)d_ws;

  // chunk length CL=4 if the slot pool fits, else 8
  int CL = 4;
  int TOTC = 0;
  for (int q = 0; q < NQB; ++q) TOTC += (2 * q + 2 + CL - 1) / CL;   // 272
  if (ws_size < (size_t)NBATCH * TOTC * SLOT_B) {
    CL = 8;
    TOTC = 0;
    for (int q = 0; q < NQB; ++q) TOTC += (2 * q + 2 + CL - 1) / CL; // 144
  }

  dim3 grid(NBATCH * TOTC);
  dim3 block(256);
  hipLaunchKernelGGL(fattn_partial, grid, block, 0, stream, Q, K, V, P, Ws,
                     CL, TOTC);
  hipLaunchKernelGGL(fattn_merge, dim3(NBATCH * NQB * 4), dim3(256), 0, stream,
                     Ws, O, CL, TOTC);
}